// Round 11
// baseline (176.564 us; speedup 1.0000x reference)
//
#include <hip/hip_runtime.h>
#include <cmath>

// ---- problem constants ----
#define WD 128
#define HT 128
#define HW 16384            // H*W
#define NB 4
#define NA 9
#define NPB (NA*HW)         // anchors per batch = 147456
#define TOPN 4000
#define POSTN 1000
#define CANDCAP 8192        // max candidates per batch (fine-bin overshoot << this)
#define MROWS 4096          // padded rows for topk buffer
#define RST 4160            // row stride (u64s) per (b,word) mask stream
#define NTILE 63            // ceil(4000/64)
#define NREP 4              // histogram replicas (contention divider)
#define PBLK 576            // 256-thread blocks per batch (NPB/256)
#define NBLK 42             // LDS-staged column blocks (covers exit <= chunk 42)

typedef unsigned long long u64;
typedef unsigned int u32;

struct Anchors { float v[36]; };

// ---------------- host: replicate numpy _generate_anchors exactly ----------------
static void gen_anchors(float* out) {
    double base[4] = {0.0, 0.0, 15.0, 15.0};
    const double ratios[3] = {0.5, 1.0, 2.0};
    const double scales[3] = {8.0, 16.0, 32.0};
    double w = base[2] - base[0] + 1.0;
    double h = base[3] - base[1] + 1.0;
    double xc = base[0] + 0.5 * (w - 1.0);
    double yc = base[1] + 0.5 * (h - 1.0);
    double size = w * h;
    double ra[3][4];
    for (int r = 0; r < 3; ++r) {
        double ws = nearbyint(sqrt(size / ratios[r]));   // np.round = half-even
        double hs = nearbyint(ws * ratios[r]);
        ra[r][0] = xc - 0.5 * (ws - 1.0);
        ra[r][1] = yc - 0.5 * (hs - 1.0);
        ra[r][2] = xc + 0.5 * (ws - 1.0);
        ra[r][3] = yc + 0.5 * (hs - 1.0);
    }
    int k = 0;
    for (int r = 0; r < 3; ++r) {
        double w2 = ra[r][2] - ra[r][0] + 1.0;
        double h2 = ra[r][3] - ra[r][1] + 1.0;
        double x2c = ra[r][0] + 0.5 * (w2 - 1.0);
        double y2c = ra[r][1] + 0.5 * (h2 - 1.0);
        for (int s = 0; s < 3; ++s) {
            double ws = w2 * scales[s], hs = h2 * scales[s];
            out[k*4+0] = (float)(x2c - 0.5 * (ws - 1.0));
            out[k*4+1] = (float)(y2c - 0.5 * (hs - 1.0));
            out[k*4+2] = (float)(x2c + 0.5 * (ws - 1.0));
            out[k*4+3] = (float)(y2c + 0.5 * (hs - 1.0));
            ++k;
        }
    }
}

__device__ __forceinline__ u32 sortable_key(float sc) {
    u32 sb = __float_as_uint(sc);
    return sb ^ ((sb & 0x80000000u) ? 0xFFFFFFFFu : 0x80000000u);
}

__device__ __forceinline__ u64 readlane64(u64 v, int l) {
    u32 lo = (u32)__builtin_amdgcn_readlane((int)(u32)v, l);
    u32 hi = (u32)__builtin_amdgcn_readlane((int)(u32)(v >> 32), l);
    return ((u64)hi << 32) | lo;
}

// ---------------- kernel 1: decode + LDS coarse histogram (top-8 key bits) ----------------
__global__ void k_props(const float* __restrict__ scores,
                        const float* __restrict__ deltas,
                        const float* __restrict__ im_info,
                        const float* __restrict__ valid_range,
                        Anchors A,
                        float4* __restrict__ props,
                        float* __restrict__ fscores,
                        u32* __restrict__ coarseH)   // [NREP][NB][256]
{
#pragma clang fp contract(off)
    __shared__ u32 lh[256];
    int tid = threadIdx.x;
    lh[tid] = 0;
    __syncthreads();

    int n = blockIdx.x * blockDim.x + tid;
    int b = n / NPB;
    int r = n - b*NPB;
    int a = r / HW;
    int p = r - a*HW;
    int hh = p >> 7;        // / W
    int ww = p & 127;       // % W

    float sx = (float)(ww * 16);
    float sy = (float)(hh * 16);
    float ax1 = A.v[a*4+0] + sx;
    float ay1 = A.v[a*4+1] + sy;
    float ax2 = A.v[a*4+2] + sx;
    float ay2 = A.v[a*4+3] + sy;

    const float* dbase = deltas + ((size_t)(b*36 + a*4))*HW + p;
    float dx = dbase[0];
    float dy = dbase[HW];
    float dw = dbase[2*HW];
    float dh = dbase[3*HW];
    float sc = scores[((size_t)(b*18 + 9 + a))*HW + p];

    float aw = ax2 - ax1 + 1.0f;
    float ah = ay2 - ay1 + 1.0f;
    float cx = ax1 + 0.5f*aw;
    float cy = ay1 + 0.5f*ah;
    float pcx = dx*aw + cx;
    float pcy = dy*ah + cy;
    float ew = (float)exp((double)dw);   // correctly-rounded f32 exp
    float eh = (float)exp((double)dh);
    float pw = ew * aw;
    float ph = eh * ah;
    float x1 = pcx - 0.5f*pw;
    float y1 = pcy - 0.5f*ph;
    float x2 = pcx + 0.5f*pw;
    float y2 = pcy + 0.5f*ph;

    float hmax = im_info[b*3+0] - 1.0f;
    float wmax = im_info[b*3+1] - 1.0f;
    x1 = fmaxf(x1, 0.0f); y1 = fmaxf(y1, 0.0f);
    x2 = fmaxf(x2, 0.0f); y2 = fmaxf(y2, 0.0f);
    x1 = fminf(x1, wmax); y1 = fminf(y1, hmax);
    x2 = fminf(x2, wmax); y2 = fminf(y2, hmax);

    float width  = x2 - x1;
    float height = y2 - y1;
    float area = width * height;
    float v0 = valid_range[b*2+0], v1 = valid_range[b*2+1];
    float mina = v0*v0, maxa = v1*v1;
    if (area < mina || area > maxa) sc = -1.0f;

    props[n] = make_float4(x1, y1, x2, y2);
    fscores[n] = sc;
    u32 key = sortable_key(sc);
    atomicAdd(&lh[key >> 24], 1u);
    __syncthreads();

    // merge nonzero bins; block is entirely within one batch (NPB % 256 == 0)
    u32 v = lh[tid];
    if (v) {
        int rep = blockIdx.x & (NREP-1);
        atomicAdd(&coarseH[((size_t)rep*NB + (u32)(n / NPB)) * 256 + tid], v);
    }
}

// ---------------- kernel 2: coarse threshold bin c* per batch ----------------
__global__ void k_findA(const u32* __restrict__ coarseH,
                        int* __restrict__ cstar, u32* __restrict__ cabove)
{
    __shared__ u32 c[256];
    int b = blockIdx.x, t = threadIdx.x;
    u32 s = 0;
    for (int rr = 0; rr < NREP; ++rr) s += coarseH[((size_t)rr*NB + b)*256 + t];
    c[t] = s;
    __syncthreads();
    if (t == 0) {
        u32 acc = 0; int i = 255;
        for (; i >= 0; --i) {
            if (acc + c[i] >= TOPN) break;
            acc += c[i];
        }
        cstar[b] = i;
        cabove[b] = acc;
    }
}

// ---------------- kernel 3: fine histogram (bits 23:16) within coarse bin c* ----------------
__global__ void k_fineHist(const float* __restrict__ fscores,
                           const int* __restrict__ cstar,
                           u32* __restrict__ fineH)   // [NREP][NB][256]
{
    int n = blockIdx.x * blockDim.x + threadIdx.x;
    if (n >= NB*NPB) return;
    int b = n / NPB;
    u32 key = sortable_key(fscores[n]);
    if ((int)(key >> 24) == cstar[b]) {
        int rep = blockIdx.x & (NREP-1);
        atomicAdd(&fineH[((size_t)rep*NB + b)*256 + ((key >> 16) & 255u)], 1u);
    }
}

// ---------------- kernel 4: exact 16-bit threshold ----------------
__global__ void k_findB(const u32* __restrict__ fineH,
                        const int* __restrict__ cstar, const u32* __restrict__ cabove,
                        u32* __restrict__ thresh16)
{
    __shared__ u32 f[256];
    int b = blockIdx.x, t = threadIdx.x;
    u32 s = 0;
    for (int rr = 0; rr < NREP; ++rr) s += fineH[((size_t)rr*NB + b)*256 + t];
    f[t] = s;
    __syncthreads();
    if (t == 0) {
        u32 acc = cabove[b]; int i = 255;
        for (; i >= 0; --i) {
            if (acc + f[i] >= TOPN) break;
            acc += f[i];
        }
        thresh16[b] = ((u32)cstar[b] << 8) | (u32)i;
    }
}

// ---------------- kernel 5a: per-block candidate counts (no atomics) ----------------
__global__ void k_count(const float* __restrict__ fscores,
                        const u32* __restrict__ thresh16,
                        u32* __restrict__ bcnt)
{
    int n = blockIdx.x * 256 + threadIdx.x;
    int b = n / NPB;
    u32 key = sortable_key(fscores[n]);
    bool cond = (key >> 16) >= thresh16[b];
    u64 m = __ballot(cond);
    __shared__ u32 wc[4];
    int wave = threadIdx.x >> 6;
    if ((threadIdx.x & 63) == 0) wc[wave] = (u32)__popcll(m);
    __syncthreads();
    if (threadIdx.x == 0) bcnt[blockIdx.x] = wc[0] + wc[1] + wc[2] + wc[3];
}

// ---------------- kernel 5b: per-batch exclusive scan of block counts ----------------
__global__ void k_scanblk(const u32* __restrict__ bcnt,
                          u32* __restrict__ bbase, u32* __restrict__ ccnt)
{
    __shared__ u32 s[PBLK];
    int b = blockIdx.x, t = threadIdx.x;      // PBLK threads
    u32 v = bcnt[b*PBLK + t];
    s[t] = v;
    __syncthreads();
    for (int d = 1; d < PBLK; d <<= 1) {
        u32 add = (t >= d) ? s[t-d] : 0;
        __syncthreads();
        s[t] += add;
        __syncthreads();
    }
    bbase[b*PBLK + t] = s[t] - v;             // exclusive prefix
    if (t == PBLK-1) ccnt[b] = s[t];          // per-batch total (plain store)
}

// ---------------- kernel 5c: emit candidates at deterministic positions ----------------
__global__ void k_emit(const float* __restrict__ fscores,
                       const u32* __restrict__ thresh16,
                       const u32* __restrict__ bbase,
                       u64* __restrict__ cand)
{
    int n = blockIdx.x * 256 + threadIdx.x;
    int b = n / NPB;
    int r = n - b*NPB;
    int a = r / HW;
    int p = r - a*HW;
    u32 key = sortable_key(fscores[n]);
    bool cond = (key >> 16) >= thresh16[b];
    u64 m = __ballot(cond);
    int lane = threadIdx.x & 63;
    int wave = threadIdx.x >> 6;
    __shared__ u32 wb[4];
    if (lane == 0) wb[wave] = (u32)__popcll(m);
    __syncthreads();
    if (cond) {
        u32 wbase = 0;
        for (int wv = 0; wv < wave; ++wv) wbase += wb[wv];
        u32 off = (u32)__popcll(m & ((1ull << lane) - 1ull));
        u32 pos = bbase[blockIdx.x] + wbase + off;
        if (pos < CANDCAP) {
            u32 t = (u32)(p*NA + a);               // reference flat index
            cand[(size_t)b*CANDCAP + pos] = ((u64)key << 32) | (u32)(~t);
        }
    }
}

// ---------------- kernel 6: global rank-sort in LDS + direct box gather ----------------
// Inner scan UNROLLED x16: 16 independent ds_read_b64 in flight per step.
__global__ void k_rank2(const u64* __restrict__ cand, const u32* __restrict__ ccnt,
                        const float4* __restrict__ props,
                        float4* __restrict__ topk)
{
    __shared__ u64 kk[CANDCAP];   // 64 KB
    __shared__ u32 ps[256];
    int b = blockIdx.y;
    u32 N = ccnt[b]; if (N > CANDCAP) N = CANDCAP;
    int tid = threadIdx.x;
    if ((u32)(blockIdx.x * 64) >= N) return;    // whole block idle
    for (u32 i = tid; i < N; i += 256) kk[i] = cand[(size_t)b*CANDCAP + i];
    __syncthreads();
    int kl = tid & 63, seg = tid >> 6;
    u32 ki = (u32)(blockIdx.x * 64 + kl);
    u64 mykey = (ki < N) ? kk[ki] : ~0ull;
    u32 segN = (N + 3) >> 2;
    u32 s0 = seg * segN;
    u32 s1 = s0 + segN; if (s1 > N) s1 = N;
    u32 pr = 0;
    u32 i = s0;
    for (; i + 16 <= s1; i += 16) {
        u64 v0 = kk[i+0],  v1 = kk[i+1],  v2 = kk[i+2],  v3 = kk[i+3];
        u64 v4 = kk[i+4],  v5 = kk[i+5],  v6 = kk[i+6],  v7 = kk[i+7];
        u64 v8 = kk[i+8],  v9 = kk[i+9],  va = kk[i+10], vb = kk[i+11];
        u64 vc = kk[i+12], vd = kk[i+13], ve = kk[i+14], vf = kk[i+15];
        pr += (v0 > mykey) + (v1 > mykey) + (v2 > mykey) + (v3 > mykey);
        pr += (v4 > mykey) + (v5 > mykey) + (v6 > mykey) + (v7 > mykey);
        pr += (v8 > mykey) + (v9 > mykey) + (va > mykey) + (vb > mykey);
        pr += (vc > mykey) + (vd > mykey) + (ve > mykey) + (vf > mykey);
    }
    for (; i < s1; ++i) pr += (kk[i] > mykey) ? 1u : 0u;
    ps[tid] = pr;
    __syncthreads();
    if (seg == 0 && ki < N) {
        u32 rank = ps[kl] + ps[kl+64] + ps[kl+128] + ps[kl+192];
        if (rank < TOPN) {
            u32 t = ~((u32)mykey);
            int a = (int)(t % 9u);
            int p = (int)(t / 9u);
            topk[(size_t)b*MROWS + rank] = props[(size_t)b*NPB + (size_t)a*HW + p];
        }
    }
}

// ---------------- kernel 7: suppression-mask tiles, TRANSPOSED store masksT[b][word][row] ----------------
__global__ void k_mask(const float4* __restrict__ topk, u64* __restrict__ masksT)
{
#pragma clang fp contract(off)
    int tj = blockIdx.x, ti = blockIdx.y, b = blockIdx.z;
    int r = threadIdx.x;           // 0..63
    int i = ti*64 + r;
    __shared__ float4 cb[64];
    __shared__ float  ca[64];
    u64 word = 0;
    if (tj >= ti) {
        int jj = tj*64 + r;
        float4 cbox = (jj < TOPN) ? topk[(size_t)b*MROWS + jj] : make_float4(0,0,0,0);
        cb[r] = cbox;
        ca[r] = (cbox.z - cbox.x + 1.0f) * (cbox.w - cbox.y + 1.0f);
        __syncthreads();
        if (i < TOPN) {
            float4 rb = topk[(size_t)b*MROWS + i];
            float rarea = (rb.z - rb.x + 1.0f) * (rb.w - rb.y + 1.0f);
            for (int q = 0; q < 64; ++q) {
                float4 cc = cb[q];
                float iw = fminf(rb.z, cc.z) - fmaxf(rb.x, cc.x) + 1.0f;
                float ih = fminf(rb.w, cc.w) - fmaxf(rb.y, cc.y) + 1.0f;
                iw = fmaxf(iw, 0.0f); ih = fmaxf(ih, 0.0f);
                float inter = iw * ih;
                float uni = (rarea + ca[q]) - inter;
                float iou = inter / uni;       // IEEE fp32 division, like numpy
                if (iou > 0.7f) word |= (1ULL << q);
            }
            int nvalid = TOPN - tj*64;
            if (nvalid < 64) word &= ((1ULL << nvalid) - 1ULL);
            if (ti == tj) {
                u64 cm = (r == 63) ? ~0ULL : ((1ULL << (r + 1)) - 1ULL);
                word &= ~cm;                   // enforce j > i
            }
        }
    }
    // lane r -> row i consecutive: coalesced 512B store per wave; rows >= TOPN get 0
    masksT[((size_t)(b*64 + tj))*RST + i] = word;
}

// ---------------- kernel 8: greedy scan — lazy column-pull + SKIP-SUPPRESSED chain ----------------
// Per chunk c: w = OR over kept prior rows of column c (LDS-staged history),
// then greedy closure iterating ONLY kept rows via find-first-set on
// remaining = ~w & valid: r = ffs(remaining); dr = readlane(D, r);
// remaining &= ~((1<<r)|dr). All chain values wave-uniform -> SALU; serial
// steps = kept rows (~1000 total) instead of all rows (~2100).
#define NMS_PLOAD(cc) { \
    int cm = ((cc) > 62) ? 62 : (cc); \
    const u64* colp = mb + (size_t)cm*RST; \
    _Pragma("unroll") \
    for (int k = 0; k < NBLK; ++k) \
        if (k <= cm) pf[k] = colp[(size_t)k*64 + lane]; \
}

#define NMS_PSTORE(cc) { \
    int cm = ((cc) > 62) ? 62 : (cc); \
    int wmax = (cm < NBLK-1) ? cm+1 : NBLK; \
    _Pragma("unroll") \
    for (int k = 0; k < NBLK; ++k) \
        if (k < wmax) colbuf[k*64 + lane] = pf[k];   /* static pf index (no scratch) */ \
}

__global__ __launch_bounds__(64, 1) void k_nms(const u64* __restrict__ masksT,
                      const float4* __restrict__ topk,
                      float* __restrict__ out)
{
    int b = blockIdx.x;
    int lane = threadIdx.x;        // 0..63

    __shared__ u64 colbuf[NBLK*64];   // 21504 B — current column's history blocks
    __shared__ u32 kmexp[64][64];     // per-(chunk,row) keep select mask
    __shared__ u64 kmw[64];           // per-chunk keep bitmask (valid-masked)

    kmw[lane] = 0ull;
#pragma unroll
    for (int k = 0; k < 64; ++k) kmexp[k][lane] = 0u;

    // fill this batch's output with [b,0,0,0,0]
    {
        float* ob = out + (size_t)b*POSTN*5;
        for (int e = lane; e < POSTN*5; e += 64)
            ob[e] = ((e % 5) == 0) ? (float)b : 0.0f;
    }

    const u64* mb = masksT + (size_t)b*64*RST;

    u64 pf[NBLK];
    NMS_PLOAD(0)
    NMS_PSTORE(0)                     // one exposed-latency stall (prologue only)
    NMS_PLOAD(1)

    int kcnt = 0;
    for (int c = 0; c < 63; ++c) {
        // ---- CHUNK(c): accumulate suppression from kept prior rows ----
        u64 acc = 0;
        int kmax = (c < NBLK) ? c : NBLK;
#pragma unroll 4
        for (int k = 0; k < kmax; ++k) {
            u32 mk = kmexp[k][lane];
            u64 v = colbuf[k*64 + lane];
            acc |= v & (((u64)mk << 32) | mk);
        }
        for (int k = NBLK; k < c; ++k) {          // correctness fallback (exit>42 only)
            u32 mk = kmexp[k][lane];
            u64 v = mb[(size_t)c*RST + (size_t)k*64 + lane];
            acc |= v & (((u64)mk << 32) | mk);
        }
        u32 alo = (u32)acc, ahi = (u32)(acc >> 32);
        for (int d = 1; d < 64; d <<= 1) { alo |= __shfl_xor(alo, d); ahi |= __shfl_xor(ahi, d); }
        u64 w = ((u64)(u32)__builtin_amdgcn_readfirstlane((int)ahi) << 32)
              |  (u32)__builtin_amdgcn_readfirstlane((int)alo);
        u64 D = (c < NBLK) ? colbuf[c*64 + lane]
                           : mb[(size_t)c*RST + (size_t)c*64 + lane];

        // ---- skip-suppressed greedy closure (kept rows only) ----
        u64 vm = (c < 62) ? ~0ull : 0xFFFFFFFFull;
        u64 remaining = (~w) & vm;
        u64 kmask = 0ull;
        while (remaining) {
            int r = __ffsll((unsigned long long)remaining) - 1;
            kmask |= (1ull << r);
            u64 dr = readlane64(D, r);             // uniform runtime lane index
            remaining &= ~((1ull << r) | dr);
        }
        kcnt += __popcll(kmask);
        if (lane == 0) kmw[c] = kmask;
        kmexp[c][lane] = ((u32)((kmask >> lane) & 1ull)) ? ~0u : 0u;

        if (kcnt >= POSTN || c == 62) break;
        NMS_PSTORE(c+1)               // LDS <- column c+1 (loads covered by CHUNK above)
        NMS_PLOAD(c+2)                // issue next column's loads
    }

    // enumerate kept rows in ascending order; lane = chunk index
    u64 keepw = kmw[lane];                  // 0 for unprocessed chunks
    int cnt = __popcll(keepw);
    int pre = cnt;
    for (int d = 1; d < 64; d <<= 1) {
        int t = __shfl_up(pre, d);
        if (lane >= d) pre += t;
    }
    int excl = pre - cnt;
    asm volatile("s_waitcnt vmcnt(0)" ::: "memory");   // fill stores drained before coord stores
    u64 wv = keepw; int rk = excl;
    while (wv) {
        int bpos = __ffsll((unsigned long long)wv) - 1;
        wv &= wv - 1;
        if (rk < POSTN) {
            int i = lane*64 + bpos;
            float4 bx = topk[(size_t)b*MROWS + i];
            float* o = out + ((size_t)b*POSTN + rk)*5;
            o[1] = bx.x; o[2] = bx.y; o[3] = bx.z; o[4] = bx.w;
        }
        ++rk;
    }
}

// ---------------- launch ----------------
extern "C" void kernel_launch(void* const* d_in, const int* in_sizes, int n_in,
                              void* d_out, int out_size, void* d_ws, size_t ws_size,
                              hipStream_t stream)
{
    const float* scores  = (const float*)d_in[0];
    const float* deltas  = (const float*)d_in[1];
    const float* im_info = (const float*)d_in[2];
    const float* vrange  = (const float*)d_in[3];
    float* out = (float*)d_out;

    char* ws = (char*)d_ws;
    size_t off = 0;
    auto alloc = [&](size_t bytes) -> void* {
        void* ptr = ws + off;
        off += (bytes + 255) & ~(size_t)255;
        return ptr;
    };
    float4* props  = (float4*)alloc((size_t)NB*NPB*sizeof(float4));        // 9.44 MB
    float* fscores = (float*) alloc((size_t)NB*NPB*sizeof(float));         // 2.36 MB
    u64*   cand    = (u64*)   alloc((size_t)NB*CANDCAP*sizeof(u64));       // 256 KB
    float4* topk   = (float4*)alloc((size_t)NB*MROWS*sizeof(float4));      // 256 KB
    u64*   masksT  = (u64*)   alloc((size_t)NB*64*RST*sizeof(u64));        // 8.52 MB
    u32*   bcnt    = (u32*)   alloc((size_t)NB*PBLK*sizeof(u32));          // 9 KB
    u32*   bbase   = (u32*)   alloc((size_t)NB*PBLK*sizeof(u32));          // 9 KB
    // small zeroed region (single memset): coarseH | fineH
    u32*   coarseH = (u32*)   alloc((size_t)NREP*NB*256*sizeof(u32));      // 16 KB
    u32*   fineH   = (u32*)   alloc((size_t)NREP*NB*256*sizeof(u32));      // 16 KB
    // outputs written every run (no init needed)
    u32*   ccnt    = (u32*)   alloc(256);
    int*   cstar   = (int*)   alloc(256);
    u32*   cabove  = (u32*)   alloc(256);
    u32*   thresh16= (u32*)   alloc(256);

    Anchors A;
    gen_anchors(A.v);

    size_t zbytes = (char*)fineH + (size_t)NREP*NB*256*sizeof(u32) - (char*)coarseH;
    hipMemsetAsync(coarseH, 0, zbytes, stream);

    int total = NB*NPB;
    k_props<<<(total + 255)/256, 256, 0, stream>>>(scores, deltas, im_info, vrange,
                                                   A, props, fscores, coarseH);
    k_findA<<<NB, 256, 0, stream>>>(coarseH, cstar, cabove);
    k_fineHist<<<(total + 255)/256, 256, 0, stream>>>(fscores, cstar, fineH);
    k_findB<<<NB, 256, 0, stream>>>(fineH, cstar, cabove, thresh16);
    k_count<<<NB*PBLK, 256, 0, stream>>>(fscores, thresh16, bcnt);
    k_scanblk<<<NB, PBLK, 0, stream>>>(bcnt, bbase, ccnt);
    k_emit<<<NB*PBLK, 256, 0, stream>>>(fscores, thresh16, bbase, cand);
    dim3 rgrid(CANDCAP/64, NB);
    k_rank2<<<rgrid, 256, 0, stream>>>(cand, ccnt, props, topk);
    dim3 mgrid(NTILE, NTILE, NB);
    k_mask<<<mgrid, 64, 0, stream>>>(topk, masksT);
    k_nms<<<NB, 64, 0, stream>>>(masksT, topk, out);
}

// Round 12
// 158.396 us; speedup vs baseline: 1.1147x; 1.1147x over previous
//
#include <hip/hip_runtime.h>
#include <cmath>

// ---- problem constants ----
#define WD 128
#define HT 128
#define HW 16384            // H*W
#define NB 4
#define NA 9
#define NPB (NA*HW)         // anchors per batch = 147456
#define TOPN 4000
#define POSTN 1000
#define CANDCAP 8192        // max candidates per batch (fine-bin overshoot << this)
#define MROWS 4096          // padded rows for topk buffer
#define RST 4160            // row stride (u64s) per (b,word) mask stream
#define NTILE 63            // ceil(4000/64)
#define NREP 4              // histogram replicas (contention divider)
#define PBLK 576            // 256-thread blocks per batch (NPB/256)
#define NBLK 42             // LDS-staged column blocks (covers exit <= chunk 42)

typedef unsigned long long u64;
typedef unsigned int u32;

struct Anchors { float v[36]; };

// ---------------- host: replicate numpy _generate_anchors exactly ----------------
static void gen_anchors(float* out) {
    double base[4] = {0.0, 0.0, 15.0, 15.0};
    const double ratios[3] = {0.5, 1.0, 2.0};
    const double scales[3] = {8.0, 16.0, 32.0};
    double w = base[2] - base[0] + 1.0;
    double h = base[3] - base[1] + 1.0;
    double xc = base[0] + 0.5 * (w - 1.0);
    double yc = base[1] + 0.5 * (h - 1.0);
    double size = w * h;
    double ra[3][4];
    for (int r = 0; r < 3; ++r) {
        double ws = nearbyint(sqrt(size / ratios[r]));   // np.round = half-even
        double hs = nearbyint(ws * ratios[r]);
        ra[r][0] = xc - 0.5 * (ws - 1.0);
        ra[r][1] = yc - 0.5 * (hs - 1.0);
        ra[r][2] = xc + 0.5 * (ws - 1.0);
        ra[r][3] = yc + 0.5 * (hs - 1.0);
    }
    int k = 0;
    for (int r = 0; r < 3; ++r) {
        double w2 = ra[r][2] - ra[r][0] + 1.0;
        double h2 = ra[r][3] - ra[r][1] + 1.0;
        double x2c = ra[r][0] + 0.5 * (w2 - 1.0);
        double y2c = ra[r][1] + 0.5 * (h2 - 1.0);
        for (int s = 0; s < 3; ++s) {
            double ws = w2 * scales[s], hs = h2 * scales[s];
            out[k*4+0] = (float)(x2c - 0.5 * (ws - 1.0));
            out[k*4+1] = (float)(y2c - 0.5 * (hs - 1.0));
            out[k*4+2] = (float)(x2c + 0.5 * (ws - 1.0));
            out[k*4+3] = (float)(y2c + 0.5 * (hs - 1.0));
            ++k;
        }
    }
}

__device__ __forceinline__ u32 sortable_key(float sc) {
    u32 sb = __float_as_uint(sc);
    return sb ^ ((sb & 0x80000000u) ? 0xFFFFFFFFu : 0x80000000u);
}

__device__ __forceinline__ u64 readlane64(u64 v, int l) {
    u32 lo = (u32)__builtin_amdgcn_readlane((int)(u32)v, l);
    u32 hi = (u32)__builtin_amdgcn_readlane((int)(u32)(v >> 32), l);
    return ((u64)hi << 32) | lo;
}

// 64-lane OR-reduce on the VALU pipe via DPP (rocPRIM pattern):
// row_shr 1/2/4/8 then row_bcast15/31; lane 63 holds the full OR.
// old=0 + bound_ctrl=false -> invalid-source lanes contribute 0 (OR identity).
__device__ __forceinline__ u64 wave_or64_dpp(u64 v) {
    u32 lo = (u32)v, hi = (u32)(v >> 32);
#define DPPOR(x, ctrl) x |= (u32)__builtin_amdgcn_update_dpp(0, (int)(x), ctrl, 0xf, 0xf, false)
    DPPOR(lo, 0x111); DPPOR(lo, 0x112); DPPOR(lo, 0x114); DPPOR(lo, 0x118);
    DPPOR(lo, 0x142); DPPOR(lo, 0x143);
    DPPOR(hi, 0x111); DPPOR(hi, 0x112); DPPOR(hi, 0x114); DPPOR(hi, 0x118);
    DPPOR(hi, 0x142); DPPOR(hi, 0x143);
#undef DPPOR
    u32 rlo = (u32)__builtin_amdgcn_readlane((int)lo, 63);
    u32 rhi = (u32)__builtin_amdgcn_readlane((int)hi, 63);
    return ((u64)rhi << 32) | rlo;
}

// ---------------- kernel 1: decode + LDS coarse histogram (top-8 key bits) ----------------
__global__ void k_props(const float* __restrict__ scores,
                        const float* __restrict__ deltas,
                        const float* __restrict__ im_info,
                        const float* __restrict__ valid_range,
                        Anchors A,
                        float4* __restrict__ props,
                        float* __restrict__ fscores,
                        u32* __restrict__ coarseH)   // [NREP][NB][256]
{
#pragma clang fp contract(off)
    __shared__ u32 lh[256];
    int tid = threadIdx.x;
    lh[tid] = 0;
    __syncthreads();

    int n = blockIdx.x * blockDim.x + tid;
    int b = n / NPB;
    int r = n - b*NPB;
    int a = r / HW;
    int p = r - a*HW;
    int hh = p >> 7;        // / W
    int ww = p & 127;       // % W

    float sx = (float)(ww * 16);
    float sy = (float)(hh * 16);
    float ax1 = A.v[a*4+0] + sx;
    float ay1 = A.v[a*4+1] + sy;
    float ax2 = A.v[a*4+2] + sx;
    float ay2 = A.v[a*4+3] + sy;

    const float* dbase = deltas + ((size_t)(b*36 + a*4))*HW + p;
    float dx = dbase[0];
    float dy = dbase[HW];
    float dw = dbase[2*HW];
    float dh = dbase[3*HW];
    float sc = scores[((size_t)(b*18 + 9 + a))*HW + p];

    float aw = ax2 - ax1 + 1.0f;
    float ah = ay2 - ay1 + 1.0f;
    float cx = ax1 + 0.5f*aw;
    float cy = ay1 + 0.5f*ah;
    float pcx = dx*aw + cx;
    float pcy = dy*ah + cy;
    float ew = (float)exp((double)dw);   // correctly-rounded f32 exp
    float eh = (float)exp((double)dh);
    float pw = ew * aw;
    float ph = eh * ah;
    float x1 = pcx - 0.5f*pw;
    float y1 = pcy - 0.5f*ph;
    float x2 = pcx + 0.5f*pw;
    float y2 = pcy + 0.5f*ph;

    float hmax = im_info[b*3+0] - 1.0f;
    float wmax = im_info[b*3+1] - 1.0f;
    x1 = fmaxf(x1, 0.0f); y1 = fmaxf(y1, 0.0f);
    x2 = fmaxf(x2, 0.0f); y2 = fmaxf(y2, 0.0f);
    x1 = fminf(x1, wmax); y1 = fminf(y1, hmax);
    x2 = fminf(x2, wmax); y2 = fminf(y2, hmax);

    float width  = x2 - x1;
    float height = y2 - y1;
    float area = width * height;
    float v0 = valid_range[b*2+0], v1 = valid_range[b*2+1];
    float mina = v0*v0, maxa = v1*v1;
    if (area < mina || area > maxa) sc = -1.0f;

    props[n] = make_float4(x1, y1, x2, y2);
    fscores[n] = sc;
    u32 key = sortable_key(sc);
    atomicAdd(&lh[key >> 24], 1u);
    __syncthreads();

    // merge nonzero bins; block is entirely within one batch (NPB % 256 == 0)
    u32 v = lh[tid];
    if (v) {
        int rep = blockIdx.x & (NREP-1);
        atomicAdd(&coarseH[((size_t)rep*NB + (u32)(n / NPB)) * 256 + tid], v);
    }
}

// ---------------- kernel 2: coarse threshold bin c* per batch ----------------
__global__ void k_findA(const u32* __restrict__ coarseH,
                        int* __restrict__ cstar, u32* __restrict__ cabove)
{
    __shared__ u32 c[256];
    int b = blockIdx.x, t = threadIdx.x;
    u32 s = 0;
    for (int rr = 0; rr < NREP; ++rr) s += coarseH[((size_t)rr*NB + b)*256 + t];
    c[t] = s;
    __syncthreads();
    if (t == 0) {
        u32 acc = 0; int i = 255;
        for (; i >= 0; --i) {
            if (acc + c[i] >= TOPN) break;
            acc += c[i];
        }
        cstar[b] = i;
        cabove[b] = acc;
    }
}

// ---------------- kernel 3: fine histogram (bits 23:16) within coarse bin c* ----------------
__global__ void k_fineHist(const float* __restrict__ fscores,
                           const int* __restrict__ cstar,
                           u32* __restrict__ fineH)   // [NREP][NB][256]
{
    int n = blockIdx.x * blockDim.x + threadIdx.x;
    if (n >= NB*NPB) return;
    int b = n / NPB;
    u32 key = sortable_key(fscores[n]);
    if ((int)(key >> 24) == cstar[b]) {
        int rep = blockIdx.x & (NREP-1);
        atomicAdd(&fineH[((size_t)rep*NB + b)*256 + ((key >> 16) & 255u)], 1u);
    }
}

// ---------------- kernel 4: exact 16-bit threshold ----------------
__global__ void k_findB(const u32* __restrict__ fineH,
                        const int* __restrict__ cstar, const u32* __restrict__ cabove,
                        u32* __restrict__ thresh16)
{
    __shared__ u32 f[256];
    int b = blockIdx.x, t = threadIdx.x;
    u32 s = 0;
    for (int rr = 0; rr < NREP; ++rr) s += fineH[((size_t)rr*NB + b)*256 + t];
    f[t] = s;
    __syncthreads();
    if (t == 0) {
        u32 acc = cabove[b]; int i = 255;
        for (; i >= 0; --i) {
            if (acc + f[i] >= TOPN) break;
            acc += f[i];
        }
        thresh16[b] = ((u32)cstar[b] << 8) | (u32)i;
    }
}

// ---------------- kernel 5a: per-block candidate counts (no atomics) ----------------
__global__ void k_count(const float* __restrict__ fscores,
                        const u32* __restrict__ thresh16,
                        u32* __restrict__ bcnt)
{
    int n = blockIdx.x * 256 + threadIdx.x;
    int b = n / NPB;
    u32 key = sortable_key(fscores[n]);
    bool cond = (key >> 16) >= thresh16[b];
    u64 m = __ballot(cond);
    __shared__ u32 wc[4];
    int wave = threadIdx.x >> 6;
    if ((threadIdx.x & 63) == 0) wc[wave] = (u32)__popcll(m);
    __syncthreads();
    if (threadIdx.x == 0) bcnt[blockIdx.x] = wc[0] + wc[1] + wc[2] + wc[3];
}

// ---------------- kernel 5b: per-batch exclusive scan of block counts ----------------
__global__ void k_scanblk(const u32* __restrict__ bcnt,
                          u32* __restrict__ bbase, u32* __restrict__ ccnt)
{
    __shared__ u32 s[PBLK];
    int b = blockIdx.x, t = threadIdx.x;      // PBLK threads
    u32 v = bcnt[b*PBLK + t];
    s[t] = v;
    __syncthreads();
    for (int d = 1; d < PBLK; d <<= 1) {
        u32 add = (t >= d) ? s[t-d] : 0;
        __syncthreads();
        s[t] += add;
        __syncthreads();
    }
    bbase[b*PBLK + t] = s[t] - v;             // exclusive prefix
    if (t == PBLK-1) ccnt[b] = s[t];          // per-batch total (plain store)
}

// ---------------- kernel 5c: emit candidates at deterministic positions ----------------
__global__ void k_emit(const float* __restrict__ fscores,
                       const u32* __restrict__ thresh16,
                       const u32* __restrict__ bbase,
                       u64* __restrict__ cand)
{
    int n = blockIdx.x * 256 + threadIdx.x;
    int b = n / NPB;
    int r = n - b*NPB;
    int a = r / HW;
    int p = r - a*HW;
    u32 key = sortable_key(fscores[n]);
    bool cond = (key >> 16) >= thresh16[b];
    u64 m = __ballot(cond);
    int lane = threadIdx.x & 63;
    int wave = threadIdx.x >> 6;
    __shared__ u32 wb[4];
    if (lane == 0) wb[wave] = (u32)__popcll(m);
    __syncthreads();
    if (cond) {
        u32 wbase = 0;
        for (int wv = 0; wv < wave; ++wv) wbase += wb[wv];
        u32 off = (u32)__popcll(m & ((1ull << lane) - 1ull));
        u32 pos = bbase[blockIdx.x] + wbase + off;
        if (pos < CANDCAP) {
            u32 t = (u32)(p*NA + a);               // reference flat index
            cand[(size_t)b*CANDCAP + pos] = ((u64)key << 32) | (u32)(~t);
        }
    }
}

// ---------------- kernel 6: global rank-sort in LDS + direct box gather ----------------
// Inner scan UNROLLED x16: 16 independent ds_read_b64 in flight per step.
__global__ void k_rank2(const u64* __restrict__ cand, const u32* __restrict__ ccnt,
                        const float4* __restrict__ props,
                        float4* __restrict__ topk)
{
    __shared__ u64 kk[CANDCAP];   // 64 KB
    __shared__ u32 ps[256];
    int b = blockIdx.y;
    u32 N = ccnt[b]; if (N > CANDCAP) N = CANDCAP;
    int tid = threadIdx.x;
    if ((u32)(blockIdx.x * 64) >= N) return;    // whole block idle
    for (u32 i = tid; i < N; i += 256) kk[i] = cand[(size_t)b*CANDCAP + i];
    __syncthreads();
    int kl = tid & 63, seg = tid >> 6;
    u32 ki = (u32)(blockIdx.x * 64 + kl);
    u64 mykey = (ki < N) ? kk[ki] : ~0ull;
    u32 segN = (N + 3) >> 2;
    u32 s0 = seg * segN;
    u32 s1 = s0 + segN; if (s1 > N) s1 = N;
    u32 pr = 0;
    u32 i = s0;
    for (; i + 16 <= s1; i += 16) {
        u64 v0 = kk[i+0],  v1 = kk[i+1],  v2 = kk[i+2],  v3 = kk[i+3];
        u64 v4 = kk[i+4],  v5 = kk[i+5],  v6 = kk[i+6],  v7 = kk[i+7];
        u64 v8 = kk[i+8],  v9 = kk[i+9],  va = kk[i+10], vb = kk[i+11];
        u64 vc = kk[i+12], vd = kk[i+13], ve = kk[i+14], vf = kk[i+15];
        pr += (v0 > mykey) + (v1 > mykey) + (v2 > mykey) + (v3 > mykey);
        pr += (v4 > mykey) + (v5 > mykey) + (v6 > mykey) + (v7 > mykey);
        pr += (v8 > mykey) + (v9 > mykey) + (va > mykey) + (vb > mykey);
        pr += (vc > mykey) + (vd > mykey) + (ve > mykey) + (vf > mykey);
    }
    for (; i < s1; ++i) pr += (kk[i] > mykey) ? 1u : 0u;
    ps[tid] = pr;
    __syncthreads();
    if (seg == 0 && ki < N) {
        u32 rank = ps[kl] + ps[kl+64] + ps[kl+128] + ps[kl+192];
        if (rank < TOPN) {
            u32 t = ~((u32)mykey);
            int a = (int)(t % 9u);
            int p = (int)(t / 9u);
            topk[(size_t)b*MROWS + rank] = props[(size_t)b*NPB + (size_t)a*HW + p];
        }
    }
}

// ---------------- kernel 7: suppression-mask tiles, TRANSPOSED store masksT[b][word][row] ----------------
__global__ void k_mask(const float4* __restrict__ topk, u64* __restrict__ masksT)
{
#pragma clang fp contract(off)
    int tj = blockIdx.x, ti = blockIdx.y, b = blockIdx.z;
    int r = threadIdx.x;           // 0..63
    int i = ti*64 + r;
    __shared__ float4 cb[64];
    __shared__ float  ca[64];
    u64 word = 0;
    if (tj >= ti) {
        int jj = tj*64 + r;
        float4 cbox = (jj < TOPN) ? topk[(size_t)b*MROWS + jj] : make_float4(0,0,0,0);
        cb[r] = cbox;
        ca[r] = (cbox.z - cbox.x + 1.0f) * (cbox.w - cbox.y + 1.0f);
        __syncthreads();
        if (i < TOPN) {
            float4 rb = topk[(size_t)b*MROWS + i];
            float rarea = (rb.z - rb.x + 1.0f) * (rb.w - rb.y + 1.0f);
            for (int q = 0; q < 64; ++q) {
                float4 cc = cb[q];
                float iw = fminf(rb.z, cc.z) - fmaxf(rb.x, cc.x) + 1.0f;
                float ih = fminf(rb.w, cc.w) - fmaxf(rb.y, cc.y) + 1.0f;
                iw = fmaxf(iw, 0.0f); ih = fmaxf(ih, 0.0f);
                float inter = iw * ih;
                float uni = (rarea + ca[q]) - inter;
                float iou = inter / uni;       // IEEE fp32 division, like numpy
                if (iou > 0.7f) word |= (1ULL << q);
            }
            int nvalid = TOPN - tj*64;
            if (nvalid < 64) word &= ((1ULL << nvalid) - 1ULL);
            if (ti == tj) {
                u64 cm = (r == 63) ? ~0ULL : ((1ULL << (r + 1)) - 1ULL);
                word &= ~cm;                   // enforce j > i
            }
        }
    }
    // lane r -> row i consecutive: coalesced 512B store per wave; rows >= TOPN get 0
    masksT[((size_t)(b*64 + tj))*RST + i] = word;
}

// ---------------- kernel 8: greedy scan — lazy column-pull, LDS-staged, DPP reduce ----------------
// Per chunk c: w = OR over kept prior rows of column c (LDS-staged history) via
// per-lane AND-select accumulate + DPP wave-OR (VALU pipe, ~60cy — replaces the
// 12-dependent-LDS-shuffle reduce), then the validated unrolled 64-row SALU
// closure (R9 form). Column c+2's blocks prefetched to registers, stored to the
// single LDS column buffer one chunk later (latency hidden under compute).
#define NMS_PLOAD(cc) { \
    int cm = ((cc) > 62) ? 62 : (cc); \
    const u64* colp = mb + (size_t)cm*RST; \
    _Pragma("unroll") \
    for (int k = 0; k < NBLK; ++k) \
        if (k <= cm) pf[k] = colp[(size_t)k*64 + lane]; \
}

#define NMS_PSTORE(cc) { \
    int cm = ((cc) > 62) ? 62 : (cc); \
    int wmax = (cm < NBLK-1) ? cm+1 : NBLK; \
    _Pragma("unroll") \
    for (int k = 0; k < NBLK; ++k) \
        if (k < wmax) colbuf[k*64 + lane] = pf[k];   /* static pf index (no scratch) */ \
}

__global__ __launch_bounds__(64, 1) void k_nms(const u64* __restrict__ masksT,
                      const float4* __restrict__ topk,
                      float* __restrict__ out)
{
    int b = blockIdx.x;
    int lane = threadIdx.x;        // 0..63

    __shared__ u64 colbuf[NBLK*64];   // 21504 B — current column's history blocks
    __shared__ u32 kmexp[64][64];     // per-(chunk,row) keep select mask
    __shared__ u64 kmw[64];           // per-chunk keep bitmask (valid-masked)

    kmw[lane] = 0ull;
#pragma unroll
    for (int k = 0; k < 64; ++k) kmexp[k][lane] = 0u;

    // fill this batch's output with [b,0,0,0,0]
    {
        float* ob = out + (size_t)b*POSTN*5;
        for (int e = lane; e < POSTN*5; e += 64)
            ob[e] = ((e % 5) == 0) ? (float)b : 0.0f;
    }

    const u64* mb = masksT + (size_t)b*64*RST;

    u64 pf[NBLK];
    NMS_PLOAD(0)
    NMS_PSTORE(0)                     // one exposed-latency stall (prologue only)
    NMS_PLOAD(1)

    int kcnt = 0;
    for (int c = 0; c < 63; ++c) {
        // ---- CHUNK(c): accumulate suppression from kept prior rows ----
        u64 acc = 0;
        int kmax = (c < NBLK) ? c : NBLK;
#pragma unroll 8
        for (int k = 0; k < kmax; ++k) {
            u32 mk = kmexp[k][lane];
            u64 v = colbuf[k*64 + lane];
            acc |= v & (((u64)mk << 32) | mk);
        }
        for (int k = NBLK; k < c; ++k) {          // correctness fallback (exit>42 only)
            u32 mk = kmexp[k][lane];
            u64 v = mb[(size_t)c*RST + (size_t)k*64 + lane];
            acc |= v & (((u64)mk << 32) | mk);
        }
        u64 w = wave_or64_dpp(acc);               // VALU-pipe wave OR (was 12 LDS shuffles)
        u64 D = (c < NBLK) ? colbuf[c*64 + lane]
                           : mb[(size_t)c*RST + (size_t)c*64 + lane];
        // ---- validated unrolled 64-row SALU closure (R9 form) ----
#pragma unroll
        for (int r = 0; r < 64; ++r) {
            u64 dr = readlane64(D, r);
            w |= (((w >> r) & 1ull) ? 0ull : dr);
        }
        u64 kmask = ~w & ((c < 62) ? ~0ull : 0xFFFFFFFFull);
        kcnt += __popcll(kmask);
        if (lane == 0) kmw[c] = kmask;
        kmexp[c][lane] = ((u32)((kmask >> lane) & 1ull)) ? ~0u : 0u;

        if (kcnt >= POSTN || c == 62) break;
        NMS_PSTORE(c+1)               // LDS <- column c+1 (loads covered by CHUNK above)
        NMS_PLOAD(c+2)                // issue next column's loads
    }

    // enumerate kept rows in ascending order; lane = chunk index
    u64 keepw = kmw[lane];                  // 0 for unprocessed chunks
    int cnt = __popcll(keepw);
    int pre = cnt;
    for (int d = 1; d < 64; d <<= 1) {
        int t = __shfl_up(pre, d);
        if (lane >= d) pre += t;
    }
    int excl = pre - cnt;
    asm volatile("s_waitcnt vmcnt(0)" ::: "memory");   // fill stores drained before coord stores
    u64 wv = keepw; int rk = excl;
    while (wv) {
        int bpos = __ffsll((unsigned long long)wv) - 1;
        wv &= wv - 1;
        if (rk < POSTN) {
            int i = lane*64 + bpos;
            float4 bx = topk[(size_t)b*MROWS + i];
            float* o = out + ((size_t)b*POSTN + rk)*5;
            o[1] = bx.x; o[2] = bx.y; o[3] = bx.z; o[4] = bx.w;
        }
        ++rk;
    }
}

// ---------------- launch ----------------
extern "C" void kernel_launch(void* const* d_in, const int* in_sizes, int n_in,
                              void* d_out, int out_size, void* d_ws, size_t ws_size,
                              hipStream_t stream)
{
    const float* scores  = (const float*)d_in[0];
    const float* deltas  = (const float*)d_in[1];
    const float* im_info = (const float*)d_in[2];
    const float* vrange  = (const float*)d_in[3];
    float* out = (float*)d_out;

    char* ws = (char*)d_ws;
    size_t off = 0;
    auto alloc = [&](size_t bytes) -> void* {
        void* ptr = ws + off;
        off += (bytes + 255) & ~(size_t)255;
        return ptr;
    };
    float4* props  = (float4*)alloc((size_t)NB*NPB*sizeof(float4));        // 9.44 MB
    float* fscores = (float*) alloc((size_t)NB*NPB*sizeof(float));         // 2.36 MB
    u64*   cand    = (u64*)   alloc((size_t)NB*CANDCAP*sizeof(u64));       // 256 KB
    float4* topk   = (float4*)alloc((size_t)NB*MROWS*sizeof(float4));      // 256 KB
    u64*   masksT  = (u64*)   alloc((size_t)NB*64*RST*sizeof(u64));        // 8.52 MB
    u32*   bcnt    = (u32*)   alloc((size_t)NB*PBLK*sizeof(u32));          // 9 KB
    u32*   bbase   = (u32*)   alloc((size_t)NB*PBLK*sizeof(u32));          // 9 KB
    // small zeroed region (single memset): coarseH | fineH
    u32*   coarseH = (u32*)   alloc((size_t)NREP*NB*256*sizeof(u32));      // 16 KB
    u32*   fineH   = (u32*)   alloc((size_t)NREP*NB*256*sizeof(u32));      // 16 KB
    // outputs written every run (no init needed)
    u32*   ccnt    = (u32*)   alloc(256);
    int*   cstar   = (int*)   alloc(256);
    u32*   cabove  = (u32*)   alloc(256);
    u32*   thresh16= (u32*)   alloc(256);

    Anchors A;
    gen_anchors(A.v);

    size_t zbytes = (char*)fineH + (size_t)NREP*NB*256*sizeof(u32) - (char*)coarseH;
    hipMemsetAsync(coarseH, 0, zbytes, stream);

    int total = NB*NPB;
    k_props<<<(total + 255)/256, 256, 0, stream>>>(scores, deltas, im_info, vrange,
                                                   A, props, fscores, coarseH);
    k_findA<<<NB, 256, 0, stream>>>(coarseH, cstar, cabove);
    k_fineHist<<<(total + 255)/256, 256, 0, stream>>>(fscores, cstar, fineH);
    k_findB<<<NB, 256, 0, stream>>>(fineH, cstar, cabove, thresh16);
    k_count<<<NB*PBLK, 256, 0, stream>>>(fscores, thresh16, bcnt);
    k_scanblk<<<NB, PBLK, 0, stream>>>(bcnt, bbase, ccnt);
    k_emit<<<NB*PBLK, 256, 0, stream>>>(fscores, thresh16, bbase, cand);
    dim3 rgrid(CANDCAP/64, NB);
    k_rank2<<<rgrid, 256, 0, stream>>>(cand, ccnt, props, topk);
    dim3 mgrid(NTILE, NTILE, NB);
    k_mask<<<mgrid, 64, 0, stream>>>(topk, masksT);
    k_nms<<<NB, 64, 0, stream>>>(masksT, topk, out);
}

// Round 13
// 155.599 us; speedup vs baseline: 1.1347x; 1.0180x over previous
//
#include <hip/hip_runtime.h>
#include <cmath>

// ---- problem constants ----
#define WD 128
#define HT 128
#define HW 16384            // H*W
#define NB 4
#define NA 9
#define NPB (NA*HW)         // anchors per batch = 147456
#define TOPN 4000
#define POSTN 1000
#define CANDCAP 8192        // max candidates per batch (fine-bin overshoot << this)
#define MROWS 4096          // padded rows for topk buffer
#define RST 4160            // row stride (u64s) per (b,word) mask stream
#define NTILE 63            // ceil(4000/64)
#define NREP 4              // histogram replicas (contention divider)
#define PBLK 576            // 256-thread blocks per batch (NPB/256)
#define NBLK 42             // LDS-staged column blocks (covers exit <= chunk 42)

typedef unsigned long long u64;
typedef unsigned int u32;

struct Anchors { float v[36]; };

// ---------------- host: replicate numpy _generate_anchors exactly ----------------
static void gen_anchors(float* out) {
    double base[4] = {0.0, 0.0, 15.0, 15.0};
    const double ratios[3] = {0.5, 1.0, 2.0};
    const double scales[3] = {8.0, 16.0, 32.0};
    double w = base[2] - base[0] + 1.0;
    double h = base[3] - base[1] + 1.0;
    double xc = base[0] + 0.5 * (w - 1.0);
    double yc = base[1] + 0.5 * (h - 1.0);
    double size = w * h;
    double ra[3][4];
    for (int r = 0; r < 3; ++r) {
        double ws = nearbyint(sqrt(size / ratios[r]));   // np.round = half-even
        double hs = nearbyint(ws * ratios[r]);
        ra[r][0] = xc - 0.5 * (ws - 1.0);
        ra[r][1] = yc - 0.5 * (hs - 1.0);
        ra[r][2] = xc + 0.5 * (ws - 1.0);
        ra[r][3] = yc + 0.5 * (hs - 1.0);
    }
    int k = 0;
    for (int r = 0; r < 3; ++r) {
        double w2 = ra[r][2] - ra[r][0] + 1.0;
        double h2 = ra[r][3] - ra[r][1] + 1.0;
        double x2c = ra[r][0] + 0.5 * (w2 - 1.0);
        double y2c = ra[r][1] + 0.5 * (h2 - 1.0);
        for (int s = 0; s < 3; ++s) {
            double ws = w2 * scales[s], hs = h2 * scales[s];
            out[k*4+0] = (float)(x2c - 0.5 * (ws - 1.0));
            out[k*4+1] = (float)(y2c - 0.5 * (hs - 1.0));
            out[k*4+2] = (float)(x2c + 0.5 * (ws - 1.0));
            out[k*4+3] = (float)(y2c + 0.5 * (hs - 1.0));
            ++k;
        }
    }
}

__device__ __forceinline__ u32 sortable_key(float sc) {
    u32 sb = __float_as_uint(sc);
    return sb ^ ((sb & 0x80000000u) ? 0xFFFFFFFFu : 0x80000000u);
}

__device__ __forceinline__ u64 readlane64(u64 v, int l) {
    u32 lo = (u32)__builtin_amdgcn_readlane((int)(u32)v, l);
    u32 hi = (u32)__builtin_amdgcn_readlane((int)(u32)(v >> 32), l);
    return ((u64)hi << 32) | lo;
}

// 64-lane OR-reduce on the VALU pipe via DPP (rocPRIM pattern):
// row_shr 1/2/4/8 then row_bcast15/31; lane 63 holds the full OR.
__device__ __forceinline__ u64 wave_or64_dpp(u64 v) {
    u32 lo = (u32)v, hi = (u32)(v >> 32);
#define DPPOR(x, ctrl) x |= (u32)__builtin_amdgcn_update_dpp(0, (int)(x), ctrl, 0xf, 0xf, false)
    DPPOR(lo, 0x111); DPPOR(lo, 0x112); DPPOR(lo, 0x114); DPPOR(lo, 0x118);
    DPPOR(lo, 0x142); DPPOR(lo, 0x143);
    DPPOR(hi, 0x111); DPPOR(hi, 0x112); DPPOR(hi, 0x114); DPPOR(hi, 0x118);
    DPPOR(hi, 0x142); DPPOR(hi, 0x143);
#undef DPPOR
    u32 rlo = (u32)__builtin_amdgcn_readlane((int)lo, 63);
    u32 rhi = (u32)__builtin_amdgcn_readlane((int)hi, 63);
    return ((u64)rhi << 32) | rlo;
}

// ---------------- kernel 1: decode + LDS coarse histogram (top-8 key bits) ----------------
__global__ void k_props(const float* __restrict__ scores,
                        const float* __restrict__ deltas,
                        const float* __restrict__ im_info,
                        const float* __restrict__ valid_range,
                        Anchors A,
                        float4* __restrict__ props,
                        float* __restrict__ fscores,
                        u32* __restrict__ coarseH)   // [NREP][NB][256]
{
#pragma clang fp contract(off)
    __shared__ u32 lh[256];
    int tid = threadIdx.x;
    lh[tid] = 0;
    __syncthreads();

    int n = blockIdx.x * blockDim.x + tid;
    int b = n / NPB;
    int r = n - b*NPB;
    int a = r / HW;
    int p = r - a*HW;
    int hh = p >> 7;        // / W
    int ww = p & 127;       // % W

    float sx = (float)(ww * 16);
    float sy = (float)(hh * 16);
    float ax1 = A.v[a*4+0] + sx;
    float ay1 = A.v[a*4+1] + sy;
    float ax2 = A.v[a*4+2] + sx;
    float ay2 = A.v[a*4+3] + sy;

    const float* dbase = deltas + ((size_t)(b*36 + a*4))*HW + p;
    float dx = dbase[0];
    float dy = dbase[HW];
    float dw = dbase[2*HW];
    float dh = dbase[3*HW];
    float sc = scores[((size_t)(b*18 + 9 + a))*HW + p];

    float aw = ax2 - ax1 + 1.0f;
    float ah = ay2 - ay1 + 1.0f;
    float cx = ax1 + 0.5f*aw;
    float cy = ay1 + 0.5f*ah;
    float pcx = dx*aw + cx;
    float pcy = dy*ah + cy;
    float ew = (float)exp((double)dw);   // correctly-rounded f32 exp
    float eh = (float)exp((double)dh);
    float pw = ew * aw;
    float ph = eh * ah;
    float x1 = pcx - 0.5f*pw;
    float y1 = pcy - 0.5f*ph;
    float x2 = pcx + 0.5f*pw;
    float y2 = pcy + 0.5f*ph;

    float hmax = im_info[b*3+0] - 1.0f;
    float wmax = im_info[b*3+1] - 1.0f;
    x1 = fmaxf(x1, 0.0f); y1 = fmaxf(y1, 0.0f);
    x2 = fmaxf(x2, 0.0f); y2 = fmaxf(y2, 0.0f);
    x1 = fminf(x1, wmax); y1 = fminf(y1, hmax);
    x2 = fminf(x2, wmax); y2 = fminf(y2, hmax);

    float width  = x2 - x1;
    float height = y2 - y1;
    float area = width * height;
    float v0 = valid_range[b*2+0], v1 = valid_range[b*2+1];
    float mina = v0*v0, maxa = v1*v1;
    if (area < mina || area > maxa) sc = -1.0f;

    props[n] = make_float4(x1, y1, x2, y2);
    fscores[n] = sc;
    u32 key = sortable_key(sc);
    atomicAdd(&lh[key >> 24], 1u);
    __syncthreads();

    // merge nonzero bins; block is entirely within one batch (NPB % 256 == 0)
    u32 v = lh[tid];
    if (v) {
        int rep = blockIdx.x & (NREP-1);
        atomicAdd(&coarseH[((size_t)rep*NB + (u32)(n / NPB)) * 256 + tid], v);
    }
}

// ---------------- kernel 2: coarse threshold bin c* per batch ----------------
__global__ void k_findA(const u32* __restrict__ coarseH,
                        int* __restrict__ cstar, u32* __restrict__ cabove)
{
    __shared__ u32 c[256];
    int b = blockIdx.x, t = threadIdx.x;
    u32 s = 0;
    for (int rr = 0; rr < NREP; ++rr) s += coarseH[((size_t)rr*NB + b)*256 + t];
    c[t] = s;
    __syncthreads();
    if (t == 0) {
        u32 acc = 0; int i = 255;
        for (; i >= 0; --i) {
            if (acc + c[i] >= TOPN) break;
            acc += c[i];
        }
        cstar[b] = i;
        cabove[b] = acc;
    }
}

// ---------------- kernel 3: fine histogram (bits 23:16) within coarse bin c* ----------------
__global__ void k_fineHist(const float* __restrict__ fscores,
                           const int* __restrict__ cstar,
                           u32* __restrict__ fineH)   // [NREP][NB][256]
{
    int n = blockIdx.x * blockDim.x + threadIdx.x;
    if (n >= NB*NPB) return;
    int b = n / NPB;
    u32 key = sortable_key(fscores[n]);
    if ((int)(key >> 24) == cstar[b]) {
        int rep = blockIdx.x & (NREP-1);
        atomicAdd(&fineH[((size_t)rep*NB + b)*256 + ((key >> 16) & 255u)], 1u);
    }
}

// ---------------- kernel 4: exact 16-bit threshold ----------------
__global__ void k_findB(const u32* __restrict__ fineH,
                        const int* __restrict__ cstar, const u32* __restrict__ cabove,
                        u32* __restrict__ thresh16)
{
    __shared__ u32 f[256];
    int b = blockIdx.x, t = threadIdx.x;
    u32 s = 0;
    for (int rr = 0; rr < NREP; ++rr) s += fineH[((size_t)rr*NB + b)*256 + t];
    f[t] = s;
    __syncthreads();
    if (t == 0) {
        u32 acc = cabove[b]; int i = 255;
        for (; i >= 0; --i) {
            if (acc + f[i] >= TOPN) break;
            acc += f[i];
        }
        thresh16[b] = ((u32)cstar[b] << 8) | (u32)i;
    }
}

// ---------------- kernel 5a: per-block candidate counts (no atomics) ----------------
__global__ void k_count(const float* __restrict__ fscores,
                        const u32* __restrict__ thresh16,
                        u32* __restrict__ bcnt)
{
    int n = blockIdx.x * 256 + threadIdx.x;
    int b = n / NPB;
    u32 key = sortable_key(fscores[n]);
    bool cond = (key >> 16) >= thresh16[b];
    u64 m = __ballot(cond);
    __shared__ u32 wc[4];
    int wave = threadIdx.x >> 6;
    if ((threadIdx.x & 63) == 0) wc[wave] = (u32)__popcll(m);
    __syncthreads();
    if (threadIdx.x == 0) bcnt[blockIdx.x] = wc[0] + wc[1] + wc[2] + wc[3];
}

// ---------------- kernel 5b: per-batch exclusive scan of block counts ----------------
__global__ void k_scanblk(const u32* __restrict__ bcnt,
                          u32* __restrict__ bbase, u32* __restrict__ ccnt)
{
    __shared__ u32 s[PBLK];
    int b = blockIdx.x, t = threadIdx.x;      // PBLK threads
    u32 v = bcnt[b*PBLK + t];
    s[t] = v;
    __syncthreads();
    for (int d = 1; d < PBLK; d <<= 1) {
        u32 add = (t >= d) ? s[t-d] : 0;
        __syncthreads();
        s[t] += add;
        __syncthreads();
    }
    bbase[b*PBLK + t] = s[t] - v;             // exclusive prefix
    if (t == PBLK-1) ccnt[b] = s[t];          // per-batch total (plain store)
}

// ---------------- kernel 5c: emit candidates at deterministic positions ----------------
__global__ void k_emit(const float* __restrict__ fscores,
                       const u32* __restrict__ thresh16,
                       const u32* __restrict__ bbase,
                       u64* __restrict__ cand)
{
    int n = blockIdx.x * 256 + threadIdx.x;
    int b = n / NPB;
    int r = n - b*NPB;
    int a = r / HW;
    int p = r - a*HW;
    u32 key = sortable_key(fscores[n]);
    bool cond = (key >> 16) >= thresh16[b];
    u64 m = __ballot(cond);
    int lane = threadIdx.x & 63;
    int wave = threadIdx.x >> 6;
    __shared__ u32 wb[4];
    if (lane == 0) wb[wave] = (u32)__popcll(m);
    __syncthreads();
    if (cond) {
        u32 wbase = 0;
        for (int wv = 0; wv < wave; ++wv) wbase += wb[wv];
        u32 off = (u32)__popcll(m & ((1ull << lane) - 1ull));
        u32 pos = bbase[blockIdx.x] + wbase + off;
        if (pos < CANDCAP) {
            u32 t = (u32)(p*NA + a);               // reference flat index
            cand[(size_t)b*CANDCAP + pos] = ((u64)key << 32) | (u32)(~t);
        }
    }
}

// ---------------- kernel 6: global rank-sort in LDS + direct box gather ----------------
// Inner scan UNROLLED x16: 16 independent ds_read_b64 in flight per step.
__global__ void k_rank2(const u64* __restrict__ cand, const u32* __restrict__ ccnt,
                        const float4* __restrict__ props,
                        float4* __restrict__ topk)
{
    __shared__ u64 kk[CANDCAP];   // 64 KB
    __shared__ u32 ps[256];
    int b = blockIdx.y;
    u32 N = ccnt[b]; if (N > CANDCAP) N = CANDCAP;
    int tid = threadIdx.x;
    if ((u32)(blockIdx.x * 64) >= N) return;    // whole block idle
    for (u32 i = tid; i < N; i += 256) kk[i] = cand[(size_t)b*CANDCAP + i];
    __syncthreads();
    int kl = tid & 63, seg = tid >> 6;
    u32 ki = (u32)(blockIdx.x * 64 + kl);
    u64 mykey = (ki < N) ? kk[ki] : ~0ull;
    u32 segN = (N + 3) >> 2;
    u32 s0 = seg * segN;
    u32 s1 = s0 + segN; if (s1 > N) s1 = N;
    u32 pr = 0;
    u32 i = s0;
    for (; i + 16 <= s1; i += 16) {
        u64 v0 = kk[i+0],  v1 = kk[i+1],  v2 = kk[i+2],  v3 = kk[i+3];
        u64 v4 = kk[i+4],  v5 = kk[i+5],  v6 = kk[i+6],  v7 = kk[i+7];
        u64 v8 = kk[i+8],  v9 = kk[i+9],  va = kk[i+10], vb = kk[i+11];
        u64 vc = kk[i+12], vd = kk[i+13], ve = kk[i+14], vf = kk[i+15];
        pr += (v0 > mykey) + (v1 > mykey) + (v2 > mykey) + (v3 > mykey);
        pr += (v4 > mykey) + (v5 > mykey) + (v6 > mykey) + (v7 > mykey);
        pr += (v8 > mykey) + (v9 > mykey) + (va > mykey) + (vb > mykey);
        pr += (vc > mykey) + (vd > mykey) + (ve > mykey) + (vf > mykey);
    }
    for (; i < s1; ++i) pr += (kk[i] > mykey) ? 1u : 0u;
    ps[tid] = pr;
    __syncthreads();
    if (seg == 0 && ki < N) {
        u32 rank = ps[kl] + ps[kl+64] + ps[kl+128] + ps[kl+192];
        if (rank < TOPN) {
            u32 t = ~((u32)mykey);
            int a = (int)(t % 9u);
            int p = (int)(t / 9u);
            topk[(size_t)b*MROWS + rank] = props[(size_t)b*NPB + (size_t)a*HW + p];
        }
    }
}

// ---------------- kernel 7: suppression-mask tiles, TRANSPOSED store masksT[b][word][row] ----------------
__global__ void k_mask(const float4* __restrict__ topk, u64* __restrict__ masksT)
{
#pragma clang fp contract(off)
    int tj = blockIdx.x, ti = blockIdx.y, b = blockIdx.z;
    int r = threadIdx.x;           // 0..63
    int i = ti*64 + r;
    __shared__ float4 cb[64];
    __shared__ float  ca[64];
    u64 word = 0;
    if (tj >= ti) {
        int jj = tj*64 + r;
        float4 cbox = (jj < TOPN) ? topk[(size_t)b*MROWS + jj] : make_float4(0,0,0,0);
        cb[r] = cbox;
        ca[r] = (cbox.z - cbox.x + 1.0f) * (cbox.w - cbox.y + 1.0f);
        __syncthreads();
        if (i < TOPN) {
            float4 rb = topk[(size_t)b*MROWS + i];
            float rarea = (rb.z - rb.x + 1.0f) * (rb.w - rb.y + 1.0f);
            for (int q = 0; q < 64; ++q) {
                float4 cc = cb[q];
                float iw = fminf(rb.z, cc.z) - fmaxf(rb.x, cc.x) + 1.0f;
                float ih = fminf(rb.w, cc.w) - fmaxf(rb.y, cc.y) + 1.0f;
                iw = fmaxf(iw, 0.0f); ih = fmaxf(ih, 0.0f);
                float inter = iw * ih;
                float uni = (rarea + ca[q]) - inter;
                float iou = inter / uni;       // IEEE fp32 division, like numpy
                if (iou > 0.7f) word |= (1ULL << q);
            }
            int nvalid = TOPN - tj*64;
            if (nvalid < 64) word &= ((1ULL << nvalid) - 1ULL);
            if (ti == tj) {
                u64 cm = (r == 63) ? ~0ULL : ((1ULL << (r + 1)) - 1ULL);
                word &= ~cm;                   // enforce j > i
            }
        }
    }
    // lane r -> row i consecutive: coalesced 512B store per wave; rows >= TOPN get 0
    masksT[((size_t)(b*64 + tj))*RST + i] = word;
}

// ---------------- kernel 8: greedy scan — lazy column-pull, FORCED-SALU closure ----------------
// Per chunk c: w = OR over kept prior rows of column c (LDS-staged history) via
// per-lane AND-select accumulate + DPP wave-OR, then a 64-row closure whose
// dependent chain is PINNED to SALU via inline asm (s_lshr/s_and/s_cselect/s_or,
// "+s" keeps w in an SGPR pair). The 128 v_readlane feeding dr stay off the
// chain (independent, compiler-hoisted).
#define NMS_PLOAD(cc) { \
    int cm = ((cc) > 62) ? 62 : (cc); \
    const u64* colp = mb + (size_t)cm*RST; \
    _Pragma("unroll") \
    for (int k = 0; k < NBLK; ++k) \
        if (k <= cm) pf[k] = colp[(size_t)k*64 + lane]; \
}

#define NMS_PSTORE(cc) { \
    int cm = ((cc) > 62) ? 62 : (cc); \
    int wmax = (cm < NBLK-1) ? cm+1 : NBLK; \
    _Pragma("unroll") \
    for (int k = 0; k < NBLK; ++k) \
        if (k < wmax) colbuf[k*64 + lane] = pf[k];   /* static pf index (no scratch) */ \
}

__global__ __launch_bounds__(64, 1) void k_nms(const u64* __restrict__ masksT,
                      const float4* __restrict__ topk,
                      float* __restrict__ out)
{
    int b = blockIdx.x;
    int lane = threadIdx.x;        // 0..63

    __shared__ u64 colbuf[NBLK*64];   // 21504 B — current column's history blocks
    __shared__ u32 kmexp[64][64];     // per-(chunk,row) keep select mask
    __shared__ u64 kmw[64];           // per-chunk keep bitmask (valid-masked)

    kmw[lane] = 0ull;
#pragma unroll
    for (int k = 0; k < 64; ++k) kmexp[k][lane] = 0u;

    // fill this batch's output with [b,0,0,0,0]
    {
        float* ob = out + (size_t)b*POSTN*5;
        for (int e = lane; e < POSTN*5; e += 64)
            ob[e] = ((e % 5) == 0) ? (float)b : 0.0f;
    }

    const u64* mb = masksT + (size_t)b*64*RST;

    u64 pf[NBLK];
    NMS_PLOAD(0)
    NMS_PSTORE(0)                     // one exposed-latency stall (prologue only)
    NMS_PLOAD(1)

    int kcnt = 0;
    for (int c = 0; c < 63; ++c) {
        // ---- CHUNK(c): accumulate suppression from kept prior rows ----
        u64 acc = 0;
        int kmax = (c < NBLK) ? c : NBLK;
#pragma unroll 8
        for (int k = 0; k < kmax; ++k) {
            u32 mk = kmexp[k][lane];
            u64 v = colbuf[k*64 + lane];
            acc |= v & (((u64)mk << 32) | mk);
        }
        for (int k = NBLK; k < c; ++k) {          // correctness fallback (exit>42 only)
            u32 mk = kmexp[k][lane];
            u64 v = mb[(size_t)c*RST + (size_t)k*64 + lane];
            acc |= v & (((u64)mk << 32) | mk);
        }
        u64 w = wave_or64_dpp(acc);               // VALU-pipe wave OR
        u64 D = (c < NBLK) ? colbuf[c*64 + lane]
                           : mb[(size_t)c*RST + (size_t)c*64 + lane];
        // ---- 64-row closure, dependent chain pinned to SALU ----
#pragma unroll
        for (int r = 0; r < 64; ++r) {
            u64 dr = readlane64(D, r);            // off-chain, hoistable
            u64 t;
            asm("s_lshr_b64 %[t], %[w], %[rr]\n\t"
                "s_and_b64 %[t], %[t], 1\n\t"      // SCC = (bit r of w)
                "s_cselect_b64 %[t], 0, %[d]\n\t"  // t = suppressed ? 0 : dr
                "s_or_b64 %[w], %[w], %[t]"
                : [w]"+s"(w), [t]"=&s"(t)
                : [d]"s"(dr), [rr]"i"(r)
                : "scc");
        }
        u64 kmask = ~w & ((c < 62) ? ~0ull : 0xFFFFFFFFull);
        kcnt += __popcll(kmask);
        if (lane == 0) kmw[c] = kmask;
        kmexp[c][lane] = ((u32)((kmask >> lane) & 1ull)) ? ~0u : 0u;

        if (kcnt >= POSTN || c == 62) break;
        NMS_PSTORE(c+1)               // LDS <- column c+1 (loads covered by CHUNK above)
        NMS_PLOAD(c+2)                // issue next column's loads
    }

    // enumerate kept rows in ascending order; lane = chunk index
    u64 keepw = kmw[lane];                  // 0 for unprocessed chunks
    int cnt = __popcll(keepw);
    int pre = cnt;
    for (int d = 1; d < 64; d <<= 1) {
        int t = __shfl_up(pre, d);
        if (lane >= d) pre += t;
    }
    int excl = pre - cnt;
    asm volatile("s_waitcnt vmcnt(0)" ::: "memory");   // fill stores drained before coord stores
    u64 wv = keepw; int rk = excl;
    while (wv) {
        int bpos = __ffsll((unsigned long long)wv) - 1;
        wv &= wv - 1;
        if (rk < POSTN) {
            int i = lane*64 + bpos;
            float4 bx = topk[(size_t)b*MROWS + i];
            float* o = out + ((size_t)b*POSTN + rk)*5;
            o[1] = bx.x; o[2] = bx.y; o[3] = bx.z; o[4] = bx.w;
        }
        ++rk;
    }
}

// ---------------- launch ----------------
extern "C" void kernel_launch(void* const* d_in, const int* in_sizes, int n_in,
                              void* d_out, int out_size, void* d_ws, size_t ws_size,
                              hipStream_t stream)
{
    const float* scores  = (const float*)d_in[0];
    const float* deltas  = (const float*)d_in[1];
    const float* im_info = (const float*)d_in[2];
    const float* vrange  = (const float*)d_in[3];
    float* out = (float*)d_out;

    char* ws = (char*)d_ws;
    size_t off = 0;
    auto alloc = [&](size_t bytes) -> void* {
        void* ptr = ws + off;
        off += (bytes + 255) & ~(size_t)255;
        return ptr;
    };
    float4* props  = (float4*)alloc((size_t)NB*NPB*sizeof(float4));        // 9.44 MB
    float* fscores = (float*) alloc((size_t)NB*NPB*sizeof(float));         // 2.36 MB
    u64*   cand    = (u64*)   alloc((size_t)NB*CANDCAP*sizeof(u64));       // 256 KB
    float4* topk   = (float4*)alloc((size_t)NB*MROWS*sizeof(float4));      // 256 KB
    u64*   masksT  = (u64*)   alloc((size_t)NB*64*RST*sizeof(u64));        // 8.52 MB
    u32*   bcnt    = (u32*)   alloc((size_t)NB*PBLK*sizeof(u32));          // 9 KB
    u32*   bbase   = (u32*)   alloc((size_t)NB*PBLK*sizeof(u32));          // 9 KB
    // small zeroed region (single memset): coarseH | fineH
    u32*   coarseH = (u32*)   alloc((size_t)NREP*NB*256*sizeof(u32));      // 16 KB
    u32*   fineH   = (u32*)   alloc((size_t)NREP*NB*256*sizeof(u32));      // 16 KB
    // outputs written every run (no init needed)
    u32*   ccnt    = (u32*)   alloc(256);
    int*   cstar   = (int*)   alloc(256);
    u32*   cabove  = (u32*)   alloc(256);
    u32*   thresh16= (u32*)   alloc(256);

    Anchors A;
    gen_anchors(A.v);

    size_t zbytes = (char*)fineH + (size_t)NREP*NB*256*sizeof(u32) - (char*)coarseH;
    hipMemsetAsync(coarseH, 0, zbytes, stream);

    int total = NB*NPB;
    k_props<<<(total + 255)/256, 256, 0, stream>>>(scores, deltas, im_info, vrange,
                                                   A, props, fscores, coarseH);
    k_findA<<<NB, 256, 0, stream>>>(coarseH, cstar, cabove);
    k_fineHist<<<(total + 255)/256, 256, 0, stream>>>(fscores, cstar, fineH);
    k_findB<<<NB, 256, 0, stream>>>(fineH, cstar, cabove, thresh16);
    k_count<<<NB*PBLK, 256, 0, stream>>>(fscores, thresh16, bcnt);
    k_scanblk<<<NB, PBLK, 0, stream>>>(bcnt, bbase, ccnt);
    k_emit<<<NB*PBLK, 256, 0, stream>>>(fscores, thresh16, bbase, cand);
    dim3 rgrid(CANDCAP/64, NB);
    k_rank2<<<rgrid, 256, 0, stream>>>(cand, ccnt, props, topk);
    dim3 mgrid(NTILE, NTILE, NB);
    k_mask<<<mgrid, 64, 0, stream>>>(topk, masksT);
    k_nms<<<NB, 64, 0, stream>>>(masksT, topk, out);
}